// Round 2
// baseline (407.521 us; speedup 1.0000x reference)
//
#include <hip/hip_runtime.h>

typedef __attribute__((ext_vector_type(8))) __bf16 bf16x8;
typedef __attribute__((ext_vector_type(8))) short short8;
typedef __attribute__((ext_vector_type(4))) float float4_;
typedef __attribute__((ext_vector_type(4))) unsigned short ushort4_;

#define ACT_STRIDE 336   // bf16 elems per point-row; cols 0..255 act, 256..335 emb(+pad)
#define EMB_COL 256

// d_ws bf16 region offsets (elements)
#define OFF_W0T 0        // [256][64]  (k<39 valid)
#define OFF_W1T 16384    // [256][256] x4
#define OFF_W2T 81920
#define OFF_W3T 147456
#define OFF_W4T 212992
#define OFF_W5T 278528   // [256][320] (k<295 valid)
#define OFF_W6T 360448   // [256][256]
#define OFF_W7T 425984   // [256][256] (cols 1..256 of W7)
#define OFF_WCT 491520   // [128][256]
#define BF16_TOTAL 524288
#define WSF_BYTE_OFF (BF16_TOTAL * 2)  // f32 region: w7sig[256], b7a[256]

__device__ __forceinline__ unsigned short f2b(float v) {
  union { float f; unsigned u; } a; a.f = v;
  unsigned r = a.u + 0x7fffu + ((a.u >> 16) & 1u);
  return (unsigned short)(r >> 16);
}
__device__ __forceinline__ float b2f(unsigned short h) {
  union { unsigned u; float f; } a; a.u = ((unsigned)h) << 16;
  return a.f;
}

// ---------------- weight prep: f32 -> bf16, transposed + K-padded ----------
__global__ __launch_bounds__(256) void prep_kernel(
    const float* __restrict__ W0, const float* __restrict__ W1,
    const float* __restrict__ W2, const float* __restrict__ W3,
    const float* __restrict__ W4, const float* __restrict__ W5,
    const float* __restrict__ W6, const float* __restrict__ W7,
    const float* __restrict__ Wc, const float* __restrict__ b7,
    unsigned short* __restrict__ wsb, float* __restrict__ wsf)
{
  int i = blockIdx.x * 256 + threadIdx.x;
  if (i < 16384) {                       // W0pT [256][64]
    int n = i >> 6, k = i & 63;
    wsb[i] = f2b(k < 39 ? W0[k * 256 + n] : 0.f);
  } else if (i < 278528) {               // W1..W4 ^T [256][256]
    int j = i - 16384; int l = j >> 16; j &= 65535;
    int n = j >> 8, k = j & 255;
    const float* W = (l == 0) ? W1 : (l == 1) ? W2 : (l == 2) ? W3 : W4;
    wsb[i] = f2b(W[k * 256 + n]);
  } else if (i < 360448) {               // W5pT [256][320]
    int j = i - 278528; int n = j / 320; int k = j - n * 320;
    wsb[i] = f2b(k < 295 ? W5[k * 256 + n] : 0.f);
  } else if (i < 425984) {               // W6T
    int j = i - 360448; int n = j >> 8, k = j & 255;
    wsb[i] = f2b(W6[k * 256 + n]);
  } else if (i < 491520) {               // W7aT = W7[:,1:257]^T
    int j = i - 425984; int n = j >> 8, k = j & 255;
    wsb[i] = f2b(W7[k * 257 + 1 + n]);
  } else if (i < 524288) {               // WcT [128][256]
    int j = i - 491520; int n = j >> 8, k = j & 255;
    wsb[i] = f2b(Wc[k * 128 + n]);
  } else if (i < 524544) {               // w7sig = W7[:,0] (f32)
    int k = i - 524288; wsf[k] = W7[k * 257];
  } else if (i < 524800) {               // b7a = b7[1:257] (f32)
    int k = i - 524544; wsf[256 + k] = b7[k + 1];
  }
}

// ------- one layer: act[64 x K] @ W[K x N] via swapped-operand MFMA --------
// A = W^T rows (neuron m), B = activations (point n). D lane holds 4
// consecutive neurons of one point -> packed ds_write_b64, row-major act.
template<int NT, bool RELU>
__device__ __forceinline__ void layer_mm(
    const unsigned short* src, int ksteps,
    const unsigned short* __restrict__ wT, int Kp,
    const float* bias,
    unsigned short* dst, int lane, int wave)
{
  const int col = lane & 15, quad = lane >> 4;
  const int n0 = wave * (NT * 16);
  float4_ acc[4][NT] = {};

  for (int ks = 0; ks < ksteps; ++ks) {
    bf16x8 bfr[4];
    const unsigned short* p = src + col * ACT_STRIDE + ks * 32 + quad * 8;
#pragma unroll
    for (int mi = 0; mi < 4; ++mi)
      bfr[mi] = *(const bf16x8*)(p + mi * 16 * ACT_STRIDE);
    const unsigned short* wp = wT + (n0 + col) * Kp + ks * 32 + quad * 8;
#pragma unroll
    for (int ni = 0; ni < NT; ++ni) {
      bf16x8 afr = *(const bf16x8*)(wp + ni * 16 * Kp);
#pragma unroll
      for (int mi = 0; mi < 4; ++mi)
        acc[mi][ni] = __builtin_amdgcn_mfma_f32_16x16x32_bf16(afr, bfr[mi], acc[mi][ni], 0, 0, 0);
    }
  }
  __syncthreads();   // all reads of act done before overwrite
#pragma unroll
  for (int ni = 0; ni < NT; ++ni) {
    const int n = n0 + ni * 16 + quad * 4;
    float4_ bv = *(const float4_*)(bias + n);
#pragma unroll
    for (int mi = 0; mi < 4; ++mi) {
      float4_ v = acc[mi][ni] + bv;
      if (RELU) {
        v.x = fmaxf(v.x, 0.f); v.y = fmaxf(v.y, 0.f);
        v.z = fmaxf(v.z, 0.f); v.w = fmaxf(v.w, 0.f);
      }
      ushort4_ pk = { f2b(v.x), f2b(v.y), f2b(v.z), f2b(v.w) };
      *(ushort4_*)(dst + (mi * 16 + col) * ACT_STRIDE + n) = pk;
    }
  }
  __syncthreads();   // writes visible before next layer reads
}

// ------------- fused NeRF forward: one ray (64 points) per block -----------
__global__ __launch_bounds__(256) void nerf_kernel(
    const float* __restrict__ pts, const float* __restrict__ dirs,
    const float* __restrict__ b0, const float* __restrict__ b1,
    const float* __restrict__ b2, const float* __restrict__ b3,
    const float* __restrict__ b4, const float* __restrict__ b5,
    const float* __restrict__ b6, const float* __restrict__ b7,
    const float* __restrict__ Wc, const float* __restrict__ bc,
    const float* __restrict__ Wo, const float* __restrict__ bo,
    const unsigned short* __restrict__ wsb, const float* __restrict__ wsf,
    float* __restrict__ out)
{
  __shared__ __align__(16) unsigned short s_act[64 * ACT_STRIDE];
  __shared__ float s_dvec[28];
  __shared__ float s_biasc[128];

  const int ray = blockIdx.x;
  const int t = threadIdx.x;
  const int lane = t & 63;
  const int wave = t >> 6;

  // xyz harmonic embedding -> s_act cols 256..335 (39 valid + zero pad)
  {
    const int m = t >> 2, q = t & 3;
    const float* pb = pts + ray * 192 + m * 3;
    const float x0 = pb[0], x1 = pb[1], x2 = pb[2];
#pragma unroll
    for (int j = 0; j < 20; ++j) {
      const int cc = q * 20 + j;
      float v = 0.f;
      if (cc < 18) {
        const float xx = (cc < 6) ? x0 : (cc < 12) ? x1 : x2;
        v = sinf(xx * (float)(1 << (cc % 6)));
      } else if (cc < 36) {
        const int c2 = cc - 18;
        const float xx = (c2 < 6) ? x0 : (c2 < 12) ? x1 : x2;
        v = cosf(xx * (float)(1 << (c2 % 6)));
      } else if (cc == 36) v = x0;
      else if (cc == 37) v = x1;
      else if (cc == 38) v = x2;
      s_act[m * ACT_STRIDE + EMB_COL + cc] = f2b(v);
    }
  }
  // direction harmonic embedding (ray-constant, 27 values)
  if (t < 27) {
    const float* db = dirs + ray * 3;
    float v;
    if (t < 12) v = sinf(db[t >> 2] * (float)(1 << (t & 3)));
    else if (t < 24) { const int j = t - 12; v = cosf(db[j >> 2] * (float)(1 << (j & 3))); }
    else v = db[t - 24];
    s_dvec[t] = v;
  }
  __syncthreads();
  // fold direction-embedding part of Wc into a per-ray bias (read at the end;
  // the many intervening layer barriers make it visible)
  if (t < 128) {
    float s = bc[t];
#pragma unroll
    for (int j = 0; j < 27; ++j) s += s_dvec[j] * Wc[(256 + j) * 128 + t];
    s_biasc[t] = s;
  }

  // trunk (emb lives in cols 256+, never overwritten)
  layer_mm<4, true >(s_act + EMB_COL, 2,  wsb + OFF_W0T, 64,  b0, s_act, lane, wave);
  layer_mm<4, true >(s_act,           8,  wsb + OFF_W1T, 256, b1, s_act, lane, wave);
  layer_mm<4, true >(s_act,           8,  wsb + OFF_W2T, 256, b2, s_act, lane, wave);
  layer_mm<4, true >(s_act,           8,  wsb + OFF_W3T, 256, b3, s_act, lane, wave);
  layer_mm<4, true >(s_act,           8,  wsb + OFF_W4T, 256, b4, s_act, lane, wave);
  layer_mm<4, true >(s_act,           10, wsb + OFF_W5T, 320, b5, s_act, lane, wave);  // skip concat
  layer_mm<4, true >(s_act,           8,  wsb + OFF_W6T, 256, b6, s_act, lane, wave);

  // sigma = relu(h6 . W7[:,0] + b7[0]); h6 currently in s_act cols 0..255
  {
    const int m = t >> 2, q4 = t & 3;
    const unsigned short* p = s_act + m * ACT_STRIDE + q4 * 64;
    const float* wsg = wsf + q4 * 64;
    float s = 0.f;
#pragma unroll
    for (int i = 0; i < 8; ++i) {
      short8 hv = *(const short8*)(p + i * 8);
      const float* w = wsg + i * 8;
      s += b2f((unsigned short)hv[0]) * w[0] + b2f((unsigned short)hv[1]) * w[1]
         + b2f((unsigned short)hv[2]) * w[2] + b2f((unsigned short)hv[3]) * w[3]
         + b2f((unsigned short)hv[4]) * w[4] + b2f((unsigned short)hv[5]) * w[5]
         + b2f((unsigned short)hv[6]) * w[6] + b2f((unsigned short)hv[7]) * w[7];
    }
    s += __shfl_xor(s, 1);
    s += __shfl_xor(s, 2);
    if (q4 == 0) out[393216 + ray * 64 + m] = fmaxf(s + b7[0], 0.f);
  }
  // NOTE: sigma reads finish before layer7's internal barrier, so the
  // overwrite of s_act below cannot race them.

  // h7c = h6 @ W7[:,1:] + b7[1:]  (no relu)
  layer_mm<4, false>(s_act, 8, wsb + OFF_W7T, 256, wsf + 256, s_act, lane, wave);
  // c = relu(h7c @ Wc[0:256] + bias_c)   (dir part folded into bias)
  layer_mm<2, true >(s_act, 8, wsb + OFF_WCT, 256, s_biasc, s_act, lane, wave);

  // color = sigmoid(c @ Wo + bo); c in s_act cols 0..127
  {
    const int m = t >> 2, q4 = t & 3;
    const unsigned short* p = s_act + m * ACT_STRIDE + q4 * 32;
    float s0 = 0.f, s1 = 0.f, s2 = 0.f;
#pragma unroll
    for (int i = 0; i < 4; ++i) {
      short8 cv = *(const short8*)(p + i * 8);
#pragma unroll
      for (int j = 0; j < 8; ++j) {
        const float c = b2f((unsigned short)cv[j]);
        const float* w = Wo + (q4 * 32 + i * 8 + j) * 3;
        s0 += c * w[0]; s1 += c * w[1]; s2 += c * w[2];
      }
    }
    s0 += __shfl_xor(s0, 1); s0 += __shfl_xor(s0, 2);
    s1 += __shfl_xor(s1, 1); s1 += __shfl_xor(s1, 2);
    s2 += __shfl_xor(s2, 1); s2 += __shfl_xor(s2, 2);
    if (q4 == 0) {
      float* oc = out + (ray * 64 + m) * 3;
      oc[0] = 1.f / (1.f + __expf(-(s0 + bo[0])));
      oc[1] = 1.f / (1.f + __expf(-(s1 + bo[1])));
      oc[2] = 1.f / (1.f + __expf(-(s2 + bo[2])));
    }
  }
}

extern "C" void kernel_launch(void* const* d_in, const int* in_sizes, int n_in,
                              void* d_out, int out_size, void* d_ws, size_t ws_size,
                              hipStream_t stream)
{
  const float* pts  = (const float*)d_in[0];
  const float* dirs = (const float*)d_in[1];
  const float* W0 = (const float*)d_in[2];   const float* b0 = (const float*)d_in[3];
  const float* W1 = (const float*)d_in[4];   const float* b1 = (const float*)d_in[5];
  const float* W2 = (const float*)d_in[6];   const float* b2 = (const float*)d_in[7];
  const float* W3 = (const float*)d_in[8];   const float* b3 = (const float*)d_in[9];
  const float* W4 = (const float*)d_in[10];  const float* b4 = (const float*)d_in[11];
  const float* W5 = (const float*)d_in[12];  const float* b5 = (const float*)d_in[13];
  const float* W6 = (const float*)d_in[14];  const float* b6 = (const float*)d_in[15];
  const float* W7 = (const float*)d_in[16];  const float* b7 = (const float*)d_in[17];
  const float* Wc = (const float*)d_in[18];  const float* bc = (const float*)d_in[19];
  const float* Wo = (const float*)d_in[20];  const float* bo = (const float*)d_in[21];

  unsigned short* wsb = (unsigned short*)d_ws;
  float* wsf = (float*)((char*)d_ws + WSF_BYTE_OFF);

  prep_kernel<<<2050, 256, 0, stream>>>(W0, W1, W2, W3, W4, W5, W6, W7, Wc, b7, wsb, wsf);
  nerf_kernel<<<2048, 256, 0, stream>>>(pts, dirs, b0, b1, b2, b3, b4, b5, b6, b7,
                                        Wc, bc, Wo, bo, wsb, wsf, (float*)d_out);
}

// Round 3
// 257.751 us; speedup vs baseline: 1.5811x; 1.5811x over previous
//
#include <hip/hip_runtime.h>

typedef __attribute__((ext_vector_type(8))) __bf16 bf16x8;
typedef __attribute__((ext_vector_type(4))) float float4_;
typedef __attribute__((ext_vector_type(4))) unsigned short ushort4_;

#define ACT_STRIDE 264   // 528 B = 33*16 -> staggered banks for b128
#define EMB_STRIDE 72    // 144 B = 9*16

// d_ws bf16 region offsets (elements). Weights stored as packed MFMA A-tiles:
// tile(nt,kt) of 512 elems; elem (n,k): off = ((n>>4)*(Kp/32)+(k>>5))*512
//                                           + ((k>>3)&3)*128 + (n&15)*8 + (k&7)
// -> a wave's A-fragment load is wT + tile*512 + lane*8 (1KB fully coalesced).
#define OFF_W0T 0        // Kp=64
#define OFF_W1T 16384    // Kp=256 x4
#define OFF_W2T 81920
#define OFF_W3T 147456
#define OFF_W4T 212992
#define OFF_W5T 278528   // Kp=320
#define OFF_W6T 360448
#define OFF_W7T 425984   // W7[:,1:257]
#define OFF_WCT 491520   // N=128, Kp=256
#define BF16_TOTAL 524288
#define WSF_BYTE_OFF (BF16_TOTAL * 2)  // f32: w7sig[256], b7a[256]

__device__ __forceinline__ unsigned short f2b(float v) {
  union { float f; unsigned u; } a; a.f = v;
  unsigned r = a.u + 0x7fffu + ((a.u >> 16) & 1u);
  return (unsigned short)(r >> 16);
}
__device__ __forceinline__ float b2f(unsigned short h) {
  union { unsigned u; float f; } a; a.u = ((unsigned)h) << 16;
  return a.f;
}

// ---------------- weight prep: coalesced reads, MFMA-tile packed ----------
__global__ __launch_bounds__(256) void prep_kernel(
    const float* __restrict__ W0, const float* __restrict__ W1,
    const float* __restrict__ W2, const float* __restrict__ W3,
    const float* __restrict__ W4, const float* __restrict__ W5,
    const float* __restrict__ W6, const float* __restrict__ W7,
    const float* __restrict__ Wc, const float* __restrict__ b7,
    unsigned short* __restrict__ wsb, float* __restrict__ wsf)
{
  int i = blockIdx.x * 256 + threadIdx.x;
  const float* src; int rs, K, Kp, n, k2; unsigned short* base;
  if (i < 8192)        { int t = i;          n = t & 255; k2 = t >> 8; src = W0; rs = 256; K = 39;  Kp = 64;  base = wsb + OFF_W0T; }
  else if (i < 139264) { int t = i - 8192;   int l = t >> 15; t &= 32767;
                         n = t & 255; k2 = t >> 8;
                         src = (l == 0) ? W1 : (l == 1) ? W2 : (l == 2) ? W3 : W4;
                         rs = 256; K = 256; Kp = 256; base = wsb + OFF_W1T + l * 65536; }
  else if (i < 180224) { int t = i - 139264; n = t & 255; k2 = t >> 8; src = W5;     rs = 256; K = 295; Kp = 320; base = wsb + OFF_W5T; }
  else if (i < 212992) { int t = i - 180224; n = t & 255; k2 = t >> 8; src = W6;     rs = 256; K = 256; Kp = 256; base = wsb + OFF_W6T; }
  else if (i < 245760) { int t = i - 212992; n = t & 255; k2 = t >> 8; src = W7 + 1; rs = 257; K = 256; Kp = 256; base = wsb + OFF_W7T; }
  else if (i < 262144) { int t = i - 245760; n = t & 127; k2 = t >> 7; src = Wc;     rs = 128; K = 256; Kp = 256; base = wsb + OFF_WCT; }
  else if (i < 262400) { int k = i - 262144; wsf[k] = W7[k * 257]; return; }
  else if (i < 262656) { int k = i - 262400; wsf[256 + k] = b7[k + 1]; return; }
  else return;
  const int k = k2 * 2;
  const float v0 = (k     < K) ? src[k * rs + n]       : 0.f;
  const float v1 = (k + 1 < K) ? src[(k + 1) * rs + n] : 0.f;
  const int off = (((n >> 4) * (Kp >> 5)) + (k >> 5)) * 512
                + ((k >> 3) & 3) * 128 + (n & 15) * 8 + (k & 7);
  const unsigned val = (unsigned)f2b(v0) | ((unsigned)f2b(v1) << 16);
  *(unsigned*)(base + off) = val;
}

// ------- one layer slice: 64 pts x 32 neurons per wave, swapped MFMA -------
// A = weight tile (neuron-major), B = acts. D: col=lane&15 -> point,
// row=4*quad+reg -> neuron -> packed 8B write into row-major dst.
template<bool RELU>
__device__ __forceinline__ void layer_mm(
    const unsigned short* src1, int stride1, int ks1,
    const unsigned short* src2, int stride2, int ks2,
    const unsigned short* __restrict__ wT, int kTiles,
    const float* bias, unsigned short* dst, int lane, int wave)
{
  const int c = lane & 15, q = lane >> 4;
  const int nt0 = wave * 2, n0 = wave * 32;
  float4_ acc[4][2] = {};

#pragma unroll
  for (int ks = 0; ks < 8; ++ks) {          // bounded; real trip = ks1
    if (ks >= ks1) break;
    bf16x8 bfr[4];
    const unsigned short* p = src1 + c * stride1 + ks * 32 + q * 8;
#pragma unroll
    for (int mi = 0; mi < 4; ++mi)
      bfr[mi] = *(const bf16x8*)(p + mi * 16 * stride1);
#pragma unroll
    for (int ni = 0; ni < 2; ++ni) {
      bf16x8 afr = *(const bf16x8*)(wT + ((nt0 + ni) * kTiles + ks) * 512 + lane * 8);
#pragma unroll
      for (int mi = 0; mi < 4; ++mi)
        acc[mi][ni] = __builtin_amdgcn_mfma_f32_16x16x32_bf16(afr, bfr[mi], acc[mi][ni], 0, 0, 0);
    }
  }
#pragma unroll
  for (int ks = 0; ks < 2; ++ks) {          // optional second source (concat)
    if (ks >= ks2) break;
    bf16x8 bfr[4];
    const unsigned short* p = src2 + c * stride2 + ks * 32 + q * 8;
#pragma unroll
    for (int mi = 0; mi < 4; ++mi)
      bfr[mi] = *(const bf16x8*)(p + mi * 16 * stride2);
#pragma unroll
    for (int ni = 0; ni < 2; ++ni) {
      bf16x8 afr = *(const bf16x8*)(wT + ((nt0 + ni) * kTiles + ks1 + ks) * 512 + lane * 8);
#pragma unroll
      for (int mi = 0; mi < 4; ++mi)
        acc[mi][ni] = __builtin_amdgcn_mfma_f32_16x16x32_bf16(afr, bfr[mi], acc[mi][ni], 0, 0, 0);
    }
  }
#pragma unroll
  for (int ni = 0; ni < 2; ++ni) {
    const int n = n0 + ni * 16 + q * 4;
    float4_ bv = *(const float4_*)(bias + n);
#pragma unroll
    for (int mi = 0; mi < 4; ++mi) {
      float4_ v = acc[mi][ni] + bv;
      if (RELU) {
        v.x = fmaxf(v.x, 0.f); v.y = fmaxf(v.y, 0.f);
        v.z = fmaxf(v.z, 0.f); v.w = fmaxf(v.w, 0.f);
      }
      ushort4_ pk = { f2b(v.x), f2b(v.y), f2b(v.z), f2b(v.w) };
      *(ushort4_*)(dst + (mi * 16 + c) * ACT_STRIDE + n) = pk;
    }
  }
}

// --------- fused NeRF forward: 1 ray (64 pts), 8 waves, ping-pong LDS ------
__global__ __launch_bounds__(512, 4) void nerf_kernel(
    const float* __restrict__ pts, const float* __restrict__ dirs,
    const float* __restrict__ b0, const float* __restrict__ b1,
    const float* __restrict__ b2, const float* __restrict__ b3,
    const float* __restrict__ b4, const float* __restrict__ b5,
    const float* __restrict__ b6, const float* __restrict__ b7,
    const float* __restrict__ Wc, const float* __restrict__ bc,
    const float* __restrict__ Wo, const float* __restrict__ bo,
    const unsigned short* __restrict__ wsb, const float* __restrict__ wsf,
    float* __restrict__ out)
{
  __shared__ __align__(16) unsigned short sA[64 * ACT_STRIDE];
  __shared__ __align__(16) unsigned short sB[64 * ACT_STRIDE];
  __shared__ __align__(16) unsigned short sE[64 * EMB_STRIDE];
  __shared__ float s_dvec[27];
  __shared__ float s_biasc[128];

  const int ray = blockIdx.x;
  const int t = threadIdx.x;
  const int lane = t & 63;
  const int wave = t >> 6;

  // xyz harmonic embedding -> sE (39 valid, zero pad to 72)
  {
    const int m = t >> 3, s8 = t & 7;
    const float* pb = pts + (ray * 64 + m) * 3;
    const float x0 = pb[0], x1 = pb[1], x2 = pb[2];
#pragma unroll
    for (int j = 0; j < 9; ++j) {
      const int cc = s8 * 9 + j;
      float v = 0.f;
      if (cc < 18) {
        const float xx = (cc < 6) ? x0 : (cc < 12) ? x1 : x2;
        v = sinf(xx * (float)(1 << (cc % 6)));
      } else if (cc < 36) {
        const int c2 = cc - 18;
        const float xx = (c2 < 6) ? x0 : (c2 < 12) ? x1 : x2;
        v = cosf(xx * (float)(1 << (c2 % 6)));
      } else if (cc == 36) v = x0;
      else if (cc == 37) v = x1;
      else if (cc == 38) v = x2;
      sE[m * EMB_STRIDE + cc] = f2b(v);
    }
  }
  if (t < 27) {   // direction harmonic embedding (ray-constant)
    const float* db = dirs + ray * 3;
    float v;
    if (t < 12) v = sinf(db[t >> 2] * (float)(1 << (t & 3)));
    else if (t < 24) { const int j = t - 12; v = cosf(db[j >> 2] * (float)(1 << (j & 3))); }
    else v = db[t - 24];
    s_dvec[t] = v;
  }
  __syncthreads();
  if (t < 128) {  // fold dir-embedding part of Wc into per-ray bias
    float s = bc[t];
#pragma unroll
    for (int j = 0; j < 27; ++j) s += s_dvec[j] * Wc[(256 + j) * 128 + t];
    s_biasc[t] = s;
  }

  // trunk: single barrier per layer via ping-pong
  layer_mm<true >(sE, EMB_STRIDE, 2, nullptr, 0, 0, wsb + OFF_W0T, 2,  b0, sA, lane, wave); __syncthreads();
  layer_mm<true >(sA, ACT_STRIDE, 8, nullptr, 0, 0, wsb + OFF_W1T, 8,  b1, sB, lane, wave); __syncthreads();
  layer_mm<true >(sB, ACT_STRIDE, 8, nullptr, 0, 0, wsb + OFF_W2T, 8,  b2, sA, lane, wave); __syncthreads();
  layer_mm<true >(sA, ACT_STRIDE, 8, nullptr, 0, 0, wsb + OFF_W3T, 8,  b3, sB, lane, wave); __syncthreads();
  layer_mm<true >(sB, ACT_STRIDE, 8, nullptr, 0, 0, wsb + OFF_W4T, 8,  b4, sA, lane, wave); __syncthreads();
  layer_mm<true >(sA, ACT_STRIDE, 8, sE, EMB_STRIDE, 2, wsb + OFF_W5T, 10, b5, sB, lane, wave); __syncthreads();
  layer_mm<true >(sB, ACT_STRIDE, 8, nullptr, 0, 0, wsb + OFF_W6T, 8,  b6, sA, lane, wave); __syncthreads();

  // sigma = relu(h6 . W7[:,0] + b7[0]); h6 in sA
  {
    const int m = t >> 3, q8 = t & 7;
    const unsigned short* p = sA + m * ACT_STRIDE + q8 * 32;
    const float* w = wsf + q8 * 32;
    float s = 0.f;
#pragma unroll
    for (int i = 0; i < 4; ++i) {
      bf16x8 hv = *(const bf16x8*)(p + i * 8);
#pragma unroll
      for (int j = 0; j < 8; ++j) s += (float)hv[j] * w[i * 8 + j];
    }
    s += __shfl_xor(s, 1); s += __shfl_xor(s, 2); s += __shfl_xor(s, 4);
    if (q8 == 0) out[393216 + ray * 64 + m] = fmaxf(s + b7[0], 0.f);
  }
  // sigma reads of sA complete before the next barrier; L7 writes only sB.

  layer_mm<false>(sA, ACT_STRIDE, 8, nullptr, 0, 0, wsb + OFF_W7T, 8, wsf + 256, sB, lane, wave); __syncthreads();
  if (wave < 4)   // Wc: 128 outputs -> waves 0..3 only (barrier stays uniform)
    layer_mm<true>(sB, ACT_STRIDE, 8, nullptr, 0, 0, wsb + OFF_WCT, 8, s_biasc, sA, lane, wave);
  __syncthreads();

  // color = sigmoid(c @ Wo + bo); c in sA cols 0..127
  {
    const int m = t >> 3, q8 = t & 7;
    const unsigned short* p = sA + m * ACT_STRIDE + q8 * 16;
    float s0 = 0.f, s1 = 0.f, s2 = 0.f;
#pragma unroll
    for (int i = 0; i < 2; ++i) {
      bf16x8 cv = *(const bf16x8*)(p + i * 8);
#pragma unroll
      for (int j = 0; j < 8; ++j) {
        const float cc = (float)cv[j];
        const float* w = Wo + (q8 * 16 + i * 8 + j) * 3;
        s0 += cc * w[0]; s1 += cc * w[1]; s2 += cc * w[2];
      }
    }
    s0 += __shfl_xor(s0, 1); s0 += __shfl_xor(s0, 2); s0 += __shfl_xor(s0, 4);
    s1 += __shfl_xor(s1, 1); s1 += __shfl_xor(s1, 2); s1 += __shfl_xor(s1, 4);
    s2 += __shfl_xor(s2, 1); s2 += __shfl_xor(s2, 2); s2 += __shfl_xor(s2, 4);
    if (q8 == 0) {
      float* oc = out + (ray * 64 + m) * 3;
      oc[0] = 1.f / (1.f + __expf(-(s0 + bo[0])));
      oc[1] = 1.f / (1.f + __expf(-(s1 + bo[1])));
      oc[2] = 1.f / (1.f + __expf(-(s2 + bo[2])));
    }
  }
}

extern "C" void kernel_launch(void* const* d_in, const int* in_sizes, int n_in,
                              void* d_out, int out_size, void* d_ws, size_t ws_size,
                              hipStream_t stream)
{
  const float* pts  = (const float*)d_in[0];
  const float* dirs = (const float*)d_in[1];
  const float* W0 = (const float*)d_in[2];   const float* b0 = (const float*)d_in[3];
  const float* W1 = (const float*)d_in[4];   const float* b1 = (const float*)d_in[5];
  const float* W2 = (const float*)d_in[6];   const float* b2 = (const float*)d_in[7];
  const float* W3 = (const float*)d_in[8];   const float* b3 = (const float*)d_in[9];
  const float* W4 = (const float*)d_in[10];  const float* b4 = (const float*)d_in[11];
  const float* W5 = (const float*)d_in[12];  const float* b5 = (const float*)d_in[13];
  const float* W6 = (const float*)d_in[14];  const float* b6 = (const float*)d_in[15];
  const float* W7 = (const float*)d_in[16];  const float* b7 = (const float*)d_in[17];
  const float* Wc = (const float*)d_in[18];  const float* bc = (const float*)d_in[19];
  const float* Wo = (const float*)d_in[20];  const float* bo = (const float*)d_in[21];

  unsigned short* wsb = (unsigned short*)d_ws;
  float* wsf = (float*)((char*)d_ws + WSF_BYTE_OFF);

  prep_kernel<<<1026, 256, 0, stream>>>(W0, W1, W2, W3, W4, W5, W6, W7, Wc, b7, wsb, wsf);
  nerf_kernel<<<2048, 512, 0, stream>>>(pts, dirs, b0, b1, b2, b3, b4, b5, b6, b7,
                                        Wc, bc, Wo, bo, wsb, wsf, (float*)d_out);
}

// Round 4
// 255.181 us; speedup vs baseline: 1.5970x; 1.0101x over previous
//
#include <hip/hip_runtime.h>

typedef __attribute__((ext_vector_type(8))) __bf16 bf16x8;
typedef __attribute__((ext_vector_type(4))) float float4_;
typedef __attribute__((ext_vector_type(4))) unsigned short ushort4_;
typedef __attribute__((ext_vector_type(8))) unsigned short ushort8_;

// Weights AND activations stored as packed MFMA fragment tiles of 512 bf16:
// tile(nt/mi, kt); elem (n|pt, k): off = tile*512 + ((k>>3)&3)*128 + (n&15)*8 + (k&7)
// -> every wave fragment load is base + lane*16B: fully coalesced / conflict-free.
#define OFF_W0T 0        // Kp=64  (KT=2)
#define OFF_W1T 16384    // Kp=256 x4
#define OFF_W2T 81920
#define OFF_W3T 147456
#define OFF_W4T 212992
#define OFF_W5T 278528   // Kp=320 (KT=10)
#define OFF_W6T 360448
#define OFF_W7T 425984   // W7[:,1:257]
#define OFF_WCT 491520   // N=128, Kp=256
#define BF16_TOTAL 524288
#define WSF_BYTE_OFF (BF16_TOTAL * 2)  // f32: w7sig[256], b7a[256]

__device__ __forceinline__ unsigned short f2b(float v) {
  union { float f; unsigned u; } a; a.f = v;
  unsigned r = a.u + 0x7fffu + ((a.u >> 16) & 1u);
  return (unsigned short)(r >> 16);
}

// ---------------- weight prep: coalesced reads, MFMA-tile packed ----------
__global__ __launch_bounds__(256) void prep_kernel(
    const float* __restrict__ W0, const float* __restrict__ W1,
    const float* __restrict__ W2, const float* __restrict__ W3,
    const float* __restrict__ W4, const float* __restrict__ W5,
    const float* __restrict__ W6, const float* __restrict__ W7,
    const float* __restrict__ Wc, const float* __restrict__ b7,
    unsigned short* __restrict__ wsb, float* __restrict__ wsf)
{
  int i = blockIdx.x * 256 + threadIdx.x;
  const float* src; int rs, K, Kp, n, k2; unsigned short* base;
  if (i < 8192)        { int t = i;          n = t & 255; k2 = t >> 8; src = W0; rs = 256; K = 39;  Kp = 64;  base = wsb + OFF_W0T; }
  else if (i < 139264) { int t = i - 8192;   int l = t >> 15; t &= 32767;
                         n = t & 255; k2 = t >> 8;
                         src = (l == 0) ? W1 : (l == 1) ? W2 : (l == 2) ? W3 : W4;
                         rs = 256; K = 256; Kp = 256; base = wsb + OFF_W1T + l * 65536; }
  else if (i < 180224) { int t = i - 139264; n = t & 255; k2 = t >> 8; src = W5;     rs = 256; K = 295; Kp = 320; base = wsb + OFF_W5T; }
  else if (i < 212992) { int t = i - 180224; n = t & 255; k2 = t >> 8; src = W6;     rs = 256; K = 256; Kp = 256; base = wsb + OFF_W6T; }
  else if (i < 245760) { int t = i - 212992; n = t & 255; k2 = t >> 8; src = W7 + 1; rs = 257; K = 256; Kp = 256; base = wsb + OFF_W7T; }
  else if (i < 262144) { int t = i - 245760; n = t & 127; k2 = t >> 7; src = Wc;     rs = 128; K = 256; Kp = 256; base = wsb + OFF_WCT; }
  else if (i < 262400) { int k = i - 262144; wsf[k] = W7[k * 257]; return; }
  else if (i < 262656) { int k = i - 262400; wsf[256 + k] = b7[k + 1]; return; }
  else return;
  const int k = k2 * 2;
  const float v0 = (k     < K) ? src[k * rs + n]       : 0.f;
  const float v1 = (k + 1 < K) ? src[(k + 1) * rs + n] : 0.f;
  const int off = (((n >> 4) * (Kp >> 5)) + (k >> 5)) * 512
                + ((k >> 3) & 3) * 128 + (n & 15) * 8 + (k & 7);
  const unsigned val = (unsigned)f2b(v0) | ((unsigned)f2b(v1) << 16);
  *(unsigned*)(base + off) = val;
}

// ------- one layer slice: 64 pts x 32 neurons per wave, swapped MFMA -------
// src/dst are tile-layout LDS act buffers: tile index = kt*4 + mi.
template<int KS1, int KS2, bool RELU>
__device__ __forceinline__ void layer_mm(
    const unsigned short* src1, const unsigned short* src2,
    const unsigned short* __restrict__ wT,
    const float* bias, unsigned short* dst, int lane, int wave)
{
  constexpr int KT = KS1 + KS2;
  const int c = lane & 15, q = lane >> 4;
  const int nt0 = wave * 2, n0 = wave * 32;
  float4_ acc[4][2] = {};

#pragma unroll
  for (int ks = 0; ks < KS1; ++ks) {
    bf16x8 bfr[4];
#pragma unroll
    for (int mi = 0; mi < 4; ++mi)
      bfr[mi] = *(const bf16x8*)(src1 + (ks * 4 + mi) * 512 + lane * 8);
#pragma unroll
    for (int ni = 0; ni < 2; ++ni) {
      bf16x8 afr = *(const bf16x8*)(wT + ((nt0 + ni) * KT + ks) * 512 + lane * 8);
#pragma unroll
      for (int mi = 0; mi < 4; ++mi)
        acc[mi][ni] = __builtin_amdgcn_mfma_f32_16x16x32_bf16(afr, bfr[mi], acc[mi][ni], 0, 0, 0);
    }
  }
#pragma unroll
  for (int ks = 0; ks < KS2; ++ks) {   // optional concat source (emb tiles)
    bf16x8 bfr[4];
#pragma unroll
    for (int mi = 0; mi < 4; ++mi)
      bfr[mi] = *(const bf16x8*)(src2 + (ks * 4 + mi) * 512 + lane * 8);
#pragma unroll
    for (int ni = 0; ni < 2; ++ni) {
      bf16x8 afr = *(const bf16x8*)(wT + ((nt0 + ni) * KT + KS1 + ks) * 512 + lane * 8);
#pragma unroll
      for (int mi = 0; mi < 4; ++mi)
        acc[mi][ni] = __builtin_amdgcn_mfma_f32_16x16x32_bf16(afr, bfr[mi], acc[mi][ni], 0, 0, 0);
    }
  }
  // epilogue: lane holds neurons base..base+3 of point mi*16+c -> one b64
  // write per (ni,mi) into the dst tile layout (next layer's k = neuron idx).
#pragma unroll
  for (int ni = 0; ni < 2; ++ni) {
    const int base = n0 + ni * 16 + q * 4;
    float4_ bv = *(const float4_*)(bias + base);
#pragma unroll
    for (int mi = 0; mi < 4; ++mi) {
      float4_ v = acc[mi][ni] + bv;
      if (RELU) {
        v.x = fmaxf(v.x, 0.f); v.y = fmaxf(v.y, 0.f);
        v.z = fmaxf(v.z, 0.f); v.w = fmaxf(v.w, 0.f);
      }
      ushort4_ pk = { f2b(v.x), f2b(v.y), f2b(v.z), f2b(v.w) };
      const int addr = ((base >> 5) * 4 + mi) * 512
                     + ((base >> 3) & 3) * 128 + c * 8 + (base & 7);
      *(ushort4_*)(dst + addr) = pk;
    }
  }
}

// --------- fused NeRF forward: 1 ray (64 pts), 8 waves, ping-pong LDS ------
__global__ __launch_bounds__(512, 4) void nerf_kernel(
    const float* __restrict__ pts, const float* __restrict__ dirs,
    const float* __restrict__ b0, const float* __restrict__ b1,
    const float* __restrict__ b2, const float* __restrict__ b3,
    const float* __restrict__ b4, const float* __restrict__ b5,
    const float* __restrict__ b6, const float* __restrict__ b7,
    const float* __restrict__ Wc, const float* __restrict__ bc,
    const float* __restrict__ Wo, const float* __restrict__ bo,
    const unsigned short* __restrict__ wsb, const float* __restrict__ wsf,
    float* __restrict__ out)
{
  __shared__ __align__(16) unsigned short sA[32 * 512];  // 32 KB
  __shared__ __align__(16) unsigned short sB[40 * 512];  // 40 KB; tiles 32..39 = emb
  __shared__ float s_dvec[27];
  __shared__ float s_biasc[128];

  const int ray = blockIdx.x;
  const int t = threadIdx.x;
  const int lane = t & 63;
  const int wave = t >> 6;
  unsigned short* sE = sB + 32 * 512;

  // xyz harmonic embedding, written directly in tile layout (64 k, zero pad).
  // thread (m = t>>3 point, s8 = t&7): cols cc = s8*8 .. s8*8+7 -> one b128.
  {
    const int m = t >> 3, s8 = t & 7;
    const float* pb = pts + (ray * 64 + m) * 3;
    const float x0 = pb[0], x1 = pb[1], x2 = pb[2];
    ushort8_ ev;
#pragma unroll
    for (int j = 0; j < 8; ++j) {
      const int cc = s8 * 8 + j;
      float v = 0.f;
      if (cc < 18) {
        const float xx = (cc < 6) ? x0 : (cc < 12) ? x1 : x2;
        v = sinf(xx * (float)(1 << (cc % 6)));
      } else if (cc < 36) {
        const int c2 = cc - 18;
        const float xx = (c2 < 6) ? x0 : (c2 < 12) ? x1 : x2;
        v = cosf(xx * (float)(1 << (c2 % 6)));
      } else if (cc == 36) v = x0;
      else if (cc == 37) v = x1;
      else if (cc == 38) v = x2;
      ev[j] = f2b(v);
    }
    *(ushort8_*)(sE + ((s8 >> 2) * 4 + (m >> 4)) * 512 + (s8 & 3) * 128 + (m & 15) * 8) = ev;
  }
  if (t < 27) {   // direction harmonic embedding (ray-constant)
    const float* db = dirs + ray * 3;
    float v;
    if (t < 12) v = sinf(db[t >> 2] * (float)(1 << (t & 3)));
    else if (t < 24) { const int j = t - 12; v = cosf(db[j >> 2] * (float)(1 << (j & 3))); }
    else v = db[t - 24];
    s_dvec[t] = v;
  }
  __syncthreads();
  if (t < 128) {  // fold dir-embedding part of Wc into per-ray bias
    float s = bc[t];
#pragma unroll
    for (int j = 0; j < 27; ++j) s += s_dvec[j] * Wc[(256 + j) * 128 + t];
    s_biasc[t] = s;
  }

  // trunk: single barrier per layer via ping-pong
  layer_mm<2, 0, true >(sE, nullptr, wsb + OFF_W0T, b0, sA, lane, wave); __syncthreads();
  layer_mm<8, 0, true >(sA, nullptr, wsb + OFF_W1T, b1, sB, lane, wave); __syncthreads();
  layer_mm<8, 0, true >(sB, nullptr, wsb + OFF_W2T, b2, sA, lane, wave); __syncthreads();
  layer_mm<8, 0, true >(sA, nullptr, wsb + OFF_W3T, b3, sB, lane, wave); __syncthreads();
  layer_mm<8, 0, true >(sB, nullptr, wsb + OFF_W4T, b4, sA, lane, wave); __syncthreads();
  layer_mm<8, 2, true >(sA, sE,      wsb + OFF_W5T, b5, sB, lane, wave); __syncthreads();  // skip concat (emb tiles disjoint from dst tiles)
  layer_mm<8, 0, true >(sB, nullptr, wsb + OFF_W6T, b6, sA, lane, wave); __syncthreads();

  // sigma = relu(h6 . W7[:,0] + b7[0]); h6 in sA (tile layout)
  {
    const int m = t >> 3, q8 = t & 7;
    const unsigned short* pbase = sA + (q8 * 4 + (m >> 4)) * 512 + (m & 15) * 8;
    const float* w = wsf + q8 * 32;
    float s = 0.f;
#pragma unroll
    for (int i8 = 0; i8 < 4; ++i8) {
      bf16x8 hv = *(const bf16x8*)(pbase + i8 * 128);
#pragma unroll
      for (int j = 0; j < 8; ++j) s += (float)hv[j] * w[i8 * 8 + j];
    }
    s += __shfl_xor(s, 1); s += __shfl_xor(s, 2); s += __shfl_xor(s, 4);
    if (q8 == 0) out[393216 + ray * 64 + m] = fmaxf(s + b7[0], 0.f);
  }
  // sigma reads sA; L7 reads sA, writes sB -> no race before next barrier.

  layer_mm<8, 0, false>(sA, nullptr, wsb + OFF_W7T, wsf + 256, sB, lane, wave); __syncthreads();
  if (wave < 4)   // Wc: 128 outputs -> waves 0..3 (barrier stays uniform)
    layer_mm<8, 0, true>(sB, nullptr, wsb + OFF_WCT, s_biasc, sA, lane, wave);
  __syncthreads();

  // color = sigmoid(c @ Wo + bo); c = 128 dims in sA tiles 0..15
  {
    const int m = t >> 3, q8 = t & 7;
    float s0 = 0.f, s1 = 0.f, s2 = 0.f;
#pragma unroll
    for (int i2 = 0; i2 < 2; ++i2) {
      const int kb = q8 * 16 + i2 * 8;
      bf16x8 cv = *(const bf16x8*)(sA + ((kb >> 5) * 4 + (m >> 4)) * 512
                                      + ((kb >> 3) & 3) * 128 + (m & 15) * 8);
#pragma unroll
      for (int j = 0; j < 8; ++j) {
        const float cc = (float)cv[j];
        const float* w = Wo + (kb + j) * 3;
        s0 += cc * w[0]; s1 += cc * w[1]; s2 += cc * w[2];
      }
    }
    s0 += __shfl_xor(s0, 1); s0 += __shfl_xor(s0, 2); s0 += __shfl_xor(s0, 4);
    s1 += __shfl_xor(s1, 1); s1 += __shfl_xor(s1, 2); s1 += __shfl_xor(s1, 4);
    s2 += __shfl_xor(s2, 1); s2 += __shfl_xor(s2, 2); s2 += __shfl_xor(s2, 4);
    if (q8 == 0) {
      float* oc = out + (ray * 64 + m) * 3;
      oc[0] = 1.f / (1.f + __expf(-(s0 + bo[0])));
      oc[1] = 1.f / (1.f + __expf(-(s1 + bo[1])));
      oc[2] = 1.f / (1.f + __expf(-(s2 + bo[2])));
    }
  }
}

extern "C" void kernel_launch(void* const* d_in, const int* in_sizes, int n_in,
                              void* d_out, int out_size, void* d_ws, size_t ws_size,
                              hipStream_t stream)
{
  const float* pts  = (const float*)d_in[0];
  const float* dirs = (const float*)d_in[1];
  const float* W0 = (const float*)d_in[2];   const float* b0 = (const float*)d_in[3];
  const float* W1 = (const float*)d_in[4];   const float* b1 = (const float*)d_in[5];
  const float* W2 = (const float*)d_in[6];   const float* b2 = (const float*)d_in[7];
  const float* W3 = (const float*)d_in[8];   const float* b3 = (const float*)d_in[9];
  const float* W4 = (const float*)d_in[10];  const float* b4 = (const float*)d_in[11];
  const float* W5 = (const float*)d_in[12];  const float* b5 = (const float*)d_in[13];
  const float* W6 = (const float*)d_in[14];  const float* b6 = (const float*)d_in[15];
  const float* W7 = (const float*)d_in[16];  const float* b7 = (const float*)d_in[17];
  const float* Wc = (const float*)d_in[18];  const float* bc = (const float*)d_in[19];
  const float* Wo = (const float*)d_in[20];  const float* bo = (const float*)d_in[21];

  unsigned short* wsb = (unsigned short*)d_ws;
  float* wsf = (float*)((char*)d_ws + WSF_BYTE_OFF);

  prep_kernel<<<1026, 256, 0, stream>>>(W0, W1, W2, W3, W4, W5, W6, W7, Wc, b7, wsb, wsf);
  nerf_kernel<<<2048, 512, 0, stream>>>(pts, dirs, b0, b1, b2, b3, b4, b5, b6, b7,
                                        Wc, bc, Wo, bo, wsb, wsf, (float*)d_out);
}

// Round 5
// 246.155 us; speedup vs baseline: 1.6555x; 1.0367x over previous
//
#include <hip/hip_runtime.h>

typedef __attribute__((ext_vector_type(8))) __bf16 bf16x8;
typedef __attribute__((ext_vector_type(4))) float float4_;
typedef __attribute__((ext_vector_type(4))) unsigned short ushort4_;
typedef __attribute__((ext_vector_type(8))) unsigned short ushort8_;

// Weights AND activations stored as packed MFMA fragment tiles of 512 bf16:
// tile(nt/mi, kt); elem (n|pt, k): off = tile*512 + ((k>>3)&3)*128 + (n&15)*8 + (k&7)
// -> every wave fragment load is base + lane*16B: fully coalesced / conflict-free.
#define OFF_W0T 0        // Kp=64  (KT=2)
#define OFF_W1T 16384    // Kp=256 x4
#define OFF_W2T 81920
#define OFF_W3T 147456
#define OFF_W4T 212992
#define OFF_W5T 278528   // Kp=320 (KT=10)
#define OFF_W6T 360448
#define OFF_W7T 425984   // W7[:,1:257]
#define OFF_WCT 491520   // N=128, Kp=256
#define BF16_TOTAL 524288
#define WSF_BYTE_OFF (BF16_TOTAL * 2)  // f32: w7sig[256], b7a[256]

__device__ __forceinline__ unsigned short f2b(float v) {
  union { float f; unsigned u; } a; a.f = v;
  unsigned r = a.u + 0x7fffu + ((a.u >> 16) & 1u);
  return (unsigned short)(r >> 16);
}

// 4x f32 -> 4x bf16 (RNE) using the gfx950 packed cvt when available.
__device__ __forceinline__ ushort4_ pack4(float4_ v) {
#if __has_builtin(__builtin_amdgcn_cvt_pk_bf16_f32)
  auto p0 = __builtin_amdgcn_cvt_pk_bf16_f32(v.x, v.y);
  auto p1 = __builtin_amdgcn_cvt_pk_bf16_f32(v.z, v.w);
  union { decltype(p0) p; unsigned u; } u0, u1;
  u0.p = p0; u1.p = p1;
  ushort4_ r;
  r.x = (unsigned short)(u0.u & 0xffffu); r.y = (unsigned short)(u0.u >> 16);
  r.z = (unsigned short)(u1.u & 0xffffu); r.w = (unsigned short)(u1.u >> 16);
  return r;
#else
  ushort4_ r; r.x = f2b(v.x); r.y = f2b(v.y); r.z = f2b(v.z); r.w = f2b(v.w);
  return r;
#endif
}

// ---------------- weight prep: coalesced reads, MFMA-tile packed ----------
__global__ __launch_bounds__(256) void prep_kernel(
    const float* __restrict__ W0, const float* __restrict__ W1,
    const float* __restrict__ W2, const float* __restrict__ W3,
    const float* __restrict__ W4, const float* __restrict__ W5,
    const float* __restrict__ W6, const float* __restrict__ W7,
    const float* __restrict__ Wc, const float* __restrict__ b7,
    unsigned short* __restrict__ wsb, float* __restrict__ wsf)
{
  int i = blockIdx.x * 256 + threadIdx.x;
  const float* src; int rs, K, Kp, n, k2; unsigned short* base;
  if (i < 8192)        { int t = i;          n = t & 255; k2 = t >> 8; src = W0; rs = 256; K = 39;  Kp = 64;  base = wsb + OFF_W0T; }
  else if (i < 139264) { int t = i - 8192;   int l = t >> 15; t &= 32767;
                         n = t & 255; k2 = t >> 8;
                         src = (l == 0) ? W1 : (l == 1) ? W2 : (l == 2) ? W3 : W4;
                         rs = 256; K = 256; Kp = 256; base = wsb + OFF_W1T + l * 65536; }
  else if (i < 180224) { int t = i - 139264; n = t & 255; k2 = t >> 8; src = W5;     rs = 256; K = 295; Kp = 320; base = wsb + OFF_W5T; }
  else if (i < 212992) { int t = i - 180224; n = t & 255; k2 = t >> 8; src = W6;     rs = 256; K = 256; Kp = 256; base = wsb + OFF_W6T; }
  else if (i < 245760) { int t = i - 212992; n = t & 255; k2 = t >> 8; src = W7 + 1; rs = 257; K = 256; Kp = 256; base = wsb + OFF_W7T; }
  else if (i < 262144) { int t = i - 245760; n = t & 127; k2 = t >> 7; src = Wc;     rs = 128; K = 256; Kp = 256; base = wsb + OFF_WCT; }
  else if (i < 262400) { int k = i - 262144; wsf[k] = W7[k * 257]; return; }
  else if (i < 262656) { int k = i - 262400; wsf[256 + k] = b7[k + 1]; return; }
  else return;
  const int k = k2 * 2;
  const float v0 = (k     < K) ? src[k * rs + n]       : 0.f;
  const float v1 = (k + 1 < K) ? src[(k + 1) * rs + n] : 0.f;
  const int off = (((n >> 4) * (Kp >> 5)) + (k >> 5)) * 512
                + ((k >> 3) & 3) * 128 + (n & 15) * 8 + (k & 7);
  const unsigned val = (unsigned)f2b(v0) | ((unsigned)f2b(v1) << 16);
  *(unsigned*)(base + off) = val;
}

// ------- one layer slice: 64 pts x 32 neurons per wave, swapped MFMA -------
// A-loads software-pipelined one k-step ahead; bias pre-loaded into acc;
// epilogue packs via v_cvt_pk_bf16_f32.
template<int KS1, int KS2, bool RELU>
__device__ __forceinline__ void layer_mm(
    const unsigned short* src1, const unsigned short* src2,
    const unsigned short* __restrict__ wT,
    const float* bias, unsigned short* dst, int lane, int wave)
{
  constexpr int KT = KS1 + KS2;
  const int c = lane & 15, q = lane >> 4;
  const int nt0 = wave * 2, n0 = wave * 32;
  const unsigned short* wl = wT + lane * 8;

  float4_ bv0 = *(const float4_*)(bias + n0 + q * 4);
  float4_ bv1 = *(const float4_*)(bias + n0 + 16 + q * 4);
  float4_ acc[4][2];
#pragma unroll
  for (int mi = 0; mi < 4; ++mi) { acc[mi][0] = bv0; acc[mi][1] = bv1; }

  bf16x8 aC0 = *(const bf16x8*)(wl + (nt0 * KT) * 512);
  bf16x8 aC1 = *(const bf16x8*)(wl + ((nt0 + 1) * KT) * 512);
#pragma unroll
  for (int ks = 0; ks < KT; ++ks) {
    bf16x8 aN0, aN1;
    if (ks + 1 < KT) {   // prefetch next k-step's weight fragments first
      aN0 = *(const bf16x8*)(wl + (nt0 * KT + ks + 1) * 512);
      aN1 = *(const bf16x8*)(wl + ((nt0 + 1) * KT + ks + 1) * 512);
    }
    const unsigned short* bsrc = (ks < KS1) ? src1 + (ks * 4) * 512
                                            : src2 + ((ks - KS1) * 4) * 512;
    bf16x8 bfr[4];
#pragma unroll
    for (int mi = 0; mi < 4; ++mi)
      bfr[mi] = *(const bf16x8*)(bsrc + mi * 512 + lane * 8);
#pragma unroll
    for (int mi = 0; mi < 4; ++mi) {
      acc[mi][0] = __builtin_amdgcn_mfma_f32_16x16x32_bf16(aC0, bfr[mi], acc[mi][0], 0, 0, 0);
      acc[mi][1] = __builtin_amdgcn_mfma_f32_16x16x32_bf16(aC1, bfr[mi], acc[mi][1], 0, 0, 0);
    }
    if (ks + 1 < KT) { aC0 = aN0; aC1 = aN1; }
  }
  // epilogue: lane holds neurons base..base+3 of point mi*16+c -> one b64
  // write per (ni,mi) into dst tile layout (next layer's k = neuron idx).
#pragma unroll
  for (int ni = 0; ni < 2; ++ni) {
    const int base = n0 + ni * 16 + q * 4;
#pragma unroll
    for (int mi = 0; mi < 4; ++mi) {
      float4_ v = acc[mi][ni];
      if (RELU) {
        v.x = fmaxf(v.x, 0.f); v.y = fmaxf(v.y, 0.f);
        v.z = fmaxf(v.z, 0.f); v.w = fmaxf(v.w, 0.f);
      }
      const int addr = ((base >> 5) * 4 + mi) * 512
                     + ((base >> 3) & 3) * 128 + c * 8 + (base & 7);
      *(ushort4_*)(dst + addr) = pack4(v);
    }
  }
}

// --------- fused NeRF forward: 1 ray (64 pts), 8 waves, ping-pong LDS ------
__global__ __launch_bounds__(512, 4) void nerf_kernel(
    const float* __restrict__ pts, const float* __restrict__ dirs,
    const float* __restrict__ b0, const float* __restrict__ b1,
    const float* __restrict__ b2, const float* __restrict__ b3,
    const float* __restrict__ b4, const float* __restrict__ b5,
    const float* __restrict__ b6, const float* __restrict__ b7,
    const float* __restrict__ Wc, const float* __restrict__ bc,
    const float* __restrict__ Wo, const float* __restrict__ bo,
    const unsigned short* __restrict__ wsb, const float* __restrict__ wsf,
    float* __restrict__ out)
{
  __shared__ __align__(16) unsigned short sA[32 * 512];  // 32 KB
  __shared__ __align__(16) unsigned short sB[40 * 512];  // 40 KB; tiles 32..39 = emb
  __shared__ float s_dvec[27];
  __shared__ float s_biasc[128];

  const int ray = blockIdx.x;
  const int t = threadIdx.x;
  const int lane = t & 63;
  const int wave = t >> 6;
  unsigned short* sE = sB + 32 * 512;

  // xyz harmonic embedding, written directly in tile layout (64 k, zero pad).
  {
    const int m = t >> 3, s8 = t & 7;
    const float* pb = pts + (ray * 64 + m) * 3;
    const float x0 = pb[0], x1 = pb[1], x2 = pb[2];
    ushort8_ ev;
#pragma unroll
    for (int j = 0; j < 8; ++j) {
      const int cc = s8 * 8 + j;
      float v = 0.f;
      if (cc < 18) {
        const float xx = (cc < 6) ? x0 : (cc < 12) ? x1 : x2;
        v = sinf(xx * (float)(1 << (cc % 6)));
      } else if (cc < 36) {
        const int c2 = cc - 18;
        const float xx = (c2 < 6) ? x0 : (c2 < 12) ? x1 : x2;
        v = cosf(xx * (float)(1 << (c2 % 6)));
      } else if (cc == 36) v = x0;
      else if (cc == 37) v = x1;
      else if (cc == 38) v = x2;
      ev[j] = f2b(v);
    }
    *(ushort8_*)(sE + ((s8 >> 2) * 4 + (m >> 4)) * 512 + (s8 & 3) * 128 + (m & 15) * 8) = ev;
  }
  if (t < 27) {   // direction harmonic embedding (ray-constant)
    const float* db = dirs + ray * 3;
    float v;
    if (t < 12) v = sinf(db[t >> 2] * (float)(1 << (t & 3)));
    else if (t < 24) { const int j = t - 12; v = cosf(db[j >> 2] * (float)(1 << (j & 3))); }
    else v = db[t - 24];
    s_dvec[t] = v;
  }
  __syncthreads();
  if (t < 128) {  // fold dir-embedding part of Wc into per-ray bias
    float s = bc[t];
#pragma unroll
    for (int j = 0; j < 27; ++j) s += s_dvec[j] * Wc[(256 + j) * 128 + t];
    s_biasc[t] = s;
  }

  // trunk: single barrier per layer via ping-pong
  layer_mm<2, 0, true >(sE, nullptr, wsb + OFF_W0T, b0, sA, lane, wave); __syncthreads();
  layer_mm<8, 0, true >(sA, nullptr, wsb + OFF_W1T, b1, sB, lane, wave); __syncthreads();
  layer_mm<8, 0, true >(sB, nullptr, wsb + OFF_W2T, b2, sA, lane, wave); __syncthreads();
  layer_mm<8, 0, true >(sA, nullptr, wsb + OFF_W3T, b3, sB, lane, wave); __syncthreads();
  layer_mm<8, 0, true >(sB, nullptr, wsb + OFF_W4T, b4, sA, lane, wave); __syncthreads();
  layer_mm<8, 2, true >(sA, sE,      wsb + OFF_W5T, b5, sB, lane, wave); __syncthreads();  // skip concat
  layer_mm<8, 0, true >(sB, nullptr, wsb + OFF_W6T, b6, sA, lane, wave); __syncthreads();

  // sigma = relu(h6 . W7[:,0] + b7[0]); h6 in sA (tile layout)
  {
    const int m = t >> 3, q8 = t & 7;
    const unsigned short* pbase = sA + (q8 * 4 + (m >> 4)) * 512 + (m & 15) * 8;
    const float* w = wsf + q8 * 32;
    float s = 0.f;
#pragma unroll
    for (int i8 = 0; i8 < 4; ++i8) {
      bf16x8 hv = *(const bf16x8*)(pbase + i8 * 128);
#pragma unroll
      for (int j = 0; j < 8; ++j) s += (float)hv[j] * w[i8 * 8 + j];
    }
    s += __shfl_xor(s, 1); s += __shfl_xor(s, 2); s += __shfl_xor(s, 4);
    if (q8 == 0) out[393216 + ray * 64 + m] = fmaxf(s + b7[0], 0.f);
  }
  // sigma reads sA; L7 reads sA, writes sB -> no race before next barrier.

  layer_mm<8, 0, false>(sA, nullptr, wsb + OFF_W7T, wsf + 256, sB, lane, wave); __syncthreads();
  if (wave < 4)   // Wc: 128 outputs -> waves 0..3 (barrier stays uniform)
    layer_mm<8, 0, true>(sB, nullptr, wsb + OFF_WCT, s_biasc, sA, lane, wave);
  __syncthreads();

  // color = sigmoid(c @ Wo + bo); c = 128 dims in sA tiles
  {
    const int m = t >> 3, q8 = t & 7;
    float s0 = 0.f, s1 = 0.f, s2 = 0.f;
#pragma unroll
    for (int i2 = 0; i2 < 2; ++i2) {
      const int kb = q8 * 16 + i2 * 8;
      bf16x8 cv = *(const bf16x8*)(sA + ((kb >> 5) * 4 + (m >> 4)) * 512
                                      + ((kb >> 3) & 3) * 128 + (m & 15) * 8);
#pragma unroll
      for (int j = 0; j < 8; ++j) {
        const float cc = (float)cv[j];
        const float* w = Wo + (kb + j) * 3;
        s0 += cc * w[0]; s1 += cc * w[1]; s2 += cc * w[2];
      }
    }
    s0 += __shfl_xor(s0, 1); s0 += __shfl_xor(s0, 2); s0 += __shfl_xor(s0, 4);
    s1 += __shfl_xor(s1, 1); s1 += __shfl_xor(s1, 2); s1 += __shfl_xor(s1, 4);
    s2 += __shfl_xor(s2, 1); s2 += __shfl_xor(s2, 2); s2 += __shfl_xor(s2, 4);
    if (q8 == 0) {
      float* oc = out + (ray * 64 + m) * 3;
      oc[0] = 1.f / (1.f + __expf(-(s0 + bo[0])));
      oc[1] = 1.f / (1.f + __expf(-(s1 + bo[1])));
      oc[2] = 1.f / (1.f + __expf(-(s2 + bo[2])));
    }
  }
}

extern "C" void kernel_launch(void* const* d_in, const int* in_sizes, int n_in,
                              void* d_out, int out_size, void* d_ws, size_t ws_size,
                              hipStream_t stream)
{
  const float* pts  = (const float*)d_in[0];
  const float* dirs = (const float*)d_in[1];
  const float* W0 = (const float*)d_in[2];   const float* b0 = (const float*)d_in[3];
  const float* W1 = (const float*)d_in[4];   const float* b1 = (const float*)d_in[5];
  const float* W2 = (const float*)d_in[6];   const float* b2 = (const float*)d_in[7];
  const float* W3 = (const float*)d_in[8];   const float* b3 = (const float*)d_in[9];
  const float* W4 = (const float*)d_in[10];  const float* b4 = (const float*)d_in[11];
  const float* W5 = (const float*)d_in[12];  const float* b5 = (const float*)d_in[13];
  const float* W6 = (const float*)d_in[14];  const float* b6 = (const float*)d_in[15];
  const float* W7 = (const float*)d_in[16];  const float* b7 = (const float*)d_in[17];
  const float* Wc = (const float*)d_in[18];  const float* bc = (const float*)d_in[19];
  const float* Wo = (const float*)d_in[20];  const float* bo = (const float*)d_in[21];

  unsigned short* wsb = (unsigned short*)d_ws;
  float* wsf = (float*)((char*)d_ws + WSF_BYTE_OFF);

  prep_kernel<<<1026, 256, 0, stream>>>(W0, W1, W2, W3, W4, W5, W6, W7, Wc, b7, wsb, wsf);
  nerf_kernel<<<2048, 512, 0, stream>>>(pts, dirs, b0, b1, b2, b3, b4, b5, b6, b7,
                                        Wc, bc, Wo, bo, wsb, wsf, (float*)d_out);
}